// Round 5
// baseline (203.112 us; speedup 1.0000x reference)
//
#include <hip/hip_runtime.h>
#include <hip/hip_bf16.h>
#include <stdint.h>

#define DEV __device__ __forceinline__

typedef __attribute__((ext_vector_type(8))) __bf16 bf16x8;
typedef __attribute__((ext_vector_type(4))) float f32x4;
typedef __attribute__((ext_vector_type(16))) float f32x16;
typedef __attribute__((ext_vector_type(4))) short short4v;
typedef __attribute__((ext_vector_type(8))) short short8v;
typedef __attribute__((ext_vector_type(4))) unsigned int uint4v;

constexpr int B_ = 4, S_ = 2048, D_ = 512, H_ = 8, DK_ = 64;
constexpr int M_ = B_ * S_;   // 8192
constexpr int K_ = D_;        // 512

// RNE float->bf16 (finite inputs only)
DEV unsigned short f2bf(float f) {
  unsigned int u = __builtin_bit_cast(unsigned int, f);
  unsigned int r = (u + 0x7fffu + ((u >> 16) & 1u)) >> 16;
  return (unsigned short)r;
}

DEV void gld16(const void* g, void* l) {
  __builtin_amdgcn_global_load_lds(
      (const __attribute__((address_space(1))) unsigned int*)g,
      (__attribute__((address_space(3))) unsigned int*)l, 16, 0, 0);
}

DEV f32x4 mfma16(bf16x8 a, bf16x8 b, f32x4 c) {
  return __builtin_amdgcn_mfma_f32_16x16x32_bf16(a, b, c, 0, 0, 0);
}
DEV f32x16 mfma32(bf16x8 a, bf16x8 b, f32x16 c) {
  return __builtin_amdgcn_mfma_f32_32x32x16_bf16(a, b, c, 0, 0, 0);
}

// ds_read_b64_tr_b16: 16-lane group reads a 128B window (4x16 bf16 subtile),
// lane m of group gets column m.
DEV short4v tr16(const void* p) {
  short4v d;
  asm volatile("ds_read_b64_tr_b16 %0, %1"
               : "=v"(d)
               : "v"((const __attribute__((address_space(3))) char*)p));
  return d;
}

DEV unsigned pkbf(float a, float b) {  // dword = {lo: bf16(a), hi: bf16(b)}
  unsigned r;
  asm("v_cvt_pk_bf16_f32 %0, %1, %2" : "=v"(r) : "v"(a), "v"(b));
  return r;
}

DEV void pl32swap(unsigned& a, unsigned& b) {  // a[32:63] <-> b[0:31]
  asm volatile("v_permlane32_swap_b32 %0, %1" : "+v"(a), "+v"(b));
}

// ---------------------------------------------------------------------------
// Kernel 1: convert all fp32 inputs to bf16 in workspace
// ---------------------------------------------------------------------------
__global__ __launch_bounds__(256) void convert_all(
    const float* __restrict__ q, const float* __restrict__ k, const float* __restrict__ v,
    const float* __restrict__ wq, const float* __restrict__ wk,
    const float* __restrict__ wv, const float* __restrict__ wo,
    unsigned short* __restrict__ xq, unsigned short* __restrict__ xk,
    unsigned short* __restrict__ xv, unsigned short* __restrict__ wqb,
    unsigned short* __restrict__ wkb, unsigned short* __restrict__ wvb,
    unsigned short* __restrict__ wob)
{
  constexpr int NX = M_ * D_;   // 2^22
  constexpr int NW = D_ * D_;   // 2^18
  constexpr int TOT = (3 * NX + 4 * NW) / 4;
  for (int u = blockIdx.x * blockDim.x + threadIdx.x; u < TOT;
       u += gridDim.x * blockDim.x) {
    int e = u * 4;
    const float* src; unsigned short* dst; int off;
    if (e < 3 * NX) {
      int t = e >> 22; off = e & (NX - 1);
      src = (t == 0) ? q : ((t == 1) ? k : v);
      dst = (t == 0) ? xq : ((t == 1) ? xk : xv);
    } else {
      int e2 = e - 3 * NX;
      int t = e2 >> 18; off = e2 & (NW - 1);
      src = (t == 0) ? wq : ((t == 1) ? wk : ((t == 2) ? wv : wo));
      dst = (t == 0) ? wqb : ((t == 1) ? wkb : ((t == 2) ? wvb : wob));
    }
    float4 f = *(const float4*)(src + off);
    short4v o;
    o.x = (short)f2bf(f.x); o.y = (short)f2bf(f.y);
    o.z = (short)f2bf(f.z); o.w = (short)f2bf(f.w);
    *(short4v*)(dst + off) = o;
  }
}

// ---------------------------------------------------------------------------
// Kernel 2: C = A[M,K] @ W[N,K]^T, bf16, XOR-swizzled LDS, m97-style
// single-buffer 2-barrier loop, 4 blocks/CU, hoisted stage pointers.
// MODE 0: BM=128, grid (4,64,3) — fused Q/K/V projections, bf16 out [M,512].
// MODE 1: BM=64,  grid (4,128)  — output projection, fp32 + bias out [M,512].
// BN=128, BK=64. 4 waves 2x2; wave tile (BM/2)x64.
// ---------------------------------------------------------------------------
template <int MODE>
__global__ __launch_bounds__(256, 4) void gemm_bt(
    const unsigned short* __restrict__ A0, const unsigned short* __restrict__ A1,
    const unsigned short* __restrict__ A2,
    const unsigned short* __restrict__ W0, const unsigned short* __restrict__ W1,
    const unsigned short* __restrict__ W2,
    unsigned short* __restrict__ O0, unsigned short* __restrict__ O1,
    unsigned short* __restrict__ O2,
    float* __restrict__ outF, const float* __restrict__ bias)
{
  constexpr int BM = (MODE == 0) ? 128 : 64;
  constexpr int BN = 128, BK = 64, NKT = K_ / BK;
  constexpr int AFR = BM / 32;  // a-frags per wave; also A-loads per wave
  __shared__ unsigned short As[BM * BK];  // 16 KB (MODE0) / 8 KB (MODE1)
  __shared__ unsigned short Bs[BN * BK];  // 16 KB
  const int tid = threadIdx.x, lane = tid & 63, wave = tid >> 6;
  const int z = blockIdx.z;
  const unsigned short* A = (MODE == 1 || z == 0) ? A0 : (z == 1 ? A1 : A2);
  const unsigned short* W = (MODE == 1 || z == 0) ? W0 : (z == 1 ? W1 : W2);
  unsigned short* outH = (MODE == 1 || z == 0) ? O0 : (z == 1 ? O1 : O2);
  const int bn0 = blockIdx.x * BN, bm0 = blockIdx.y * BM;
  const int wr = (wave >> 1) * (BM / 2), wc = (wave & 1) * 64;
  const int frow = lane & 15, fk16 = (lane >> 4) * 16;

  // hoisted staging source pointers + LDS dest offsets (kt term added in-loop)
  const char* srcA[AFR];
  int dstA[AFR];
#pragma unroll
  for (int i = 0; i < AFR; ++i) {
    int o = (wave * AFR + i) * 1024;
    int ol = o + lane * 16;
    int row = ol >> 7, off = (ol ^ ((row & 7) << 4)) & 127;
    srcA[i] = (const char*)A + (size_t)(bm0 + row) * (K_ * 2) + off;
    dstA[i] = o;
  }
  const char* srcB[4];
  int dstB[4];
#pragma unroll
  for (int i = 0; i < 4; ++i) {
    int o = (wave * 4 + i) * 1024;
    int ol = o + lane * 16;
    int row = ol >> 7, off = (ol ^ ((row & 7) << 4)) & 127;
    srcB[i] = (const char*)W + (size_t)(bn0 + row) * (K_ * 2) + off;
    dstB[i] = o;
  }

  f32x4 acc[AFR][4];
#pragma unroll
  for (int i = 0; i < AFR; ++i)
#pragma unroll
    for (int j = 0; j < 4; ++j)
#pragma unroll
      for (int r = 0; r < 4; ++r) acc[i][j][r] = 0.f;

  for (int kt = 0; kt < NKT; ++kt) {
    __syncthreads();  // all waves done reading previous tile
#pragma unroll
    for (int i = 0; i < AFR; ++i) gld16(srcA[i] + kt * 128, (char*)As + dstA[i]);
#pragma unroll
    for (int i = 0; i < 4; ++i)   gld16(srcB[i] + kt * 128, (char*)Bs + dstB[i]);
    __syncthreads();  // staged data visible (vmcnt drained)
#pragma unroll
    for (int kc = 0; kc < 2; ++kc) {
      bf16x8 a[AFR], b[4];
#pragma unroll
      for (int i = 0; i < AFR; ++i) {
        int row = wr + i * 16 + frow;
        a[i] = *(const bf16x8*)((const char*)As +
                ((row * 128 + kc * 64 + fk16) ^ ((row & 7) << 4)));
      }
#pragma unroll
      for (int j = 0; j < 4; ++j) {
        int row = wc + j * 16 + frow;
        b[j] = *(const bf16x8*)((const char*)Bs +
                ((row * 128 + kc * 64 + fk16) ^ ((row & 7) << 4)));
      }
      __builtin_amdgcn_s_setprio(1);
#pragma unroll
      for (int i = 0; i < AFR; ++i)
#pragma unroll
        for (int j = 0; j < 4; ++j)
          acc[i][j] = mfma16(a[i], b[j], acc[i][j]);
      __builtin_amdgcn_s_setprio(0);
    }
  }

  // epilogue: C/D layout col = lane&15, row = (lane>>4)*4 + reg
  const int r0 = (lane >> 4) * 4, cn = lane & 15;
  float bv[4];
  if (MODE == 1) {
#pragma unroll
    for (int j = 0; j < 4; ++j) bv[j] = bias[bn0 + wc + j * 16 + cn];
  }
#pragma unroll
  for (int i = 0; i < AFR; ++i)
#pragma unroll
    for (int j = 0; j < 4; ++j)
#pragma unroll
      for (int r = 0; r < 4; ++r) {
        int gm = bm0 + wr + i * 16 + r0 + r;
        int gn = bn0 + wc + j * 16 + cn;
        float val = acc[i][j][r];
        if (MODE == 0) outH[(size_t)gm * D_ + gn] = f2bf(val);
        else           outF[(size_t)gm * D_ + gn] = val + bv[j];
      }
}

// ---------------------------------------------------------------------------
// Kernel 3: flash attention, 32x32 MFMA, swapped QK^T, in-register softmax
// (round-2/4 proven core — UNCHANGED this round).
// Q/K/V in [M,512] layout, head h at cols h*64..h*64+63 (row stride 1024 B).
// Grid (S/128, B*H); 4 waves x 32 q-rows. KVB=64, K/V double-buffered.
// ---------------------------------------------------------------------------
__global__ __launch_bounds__(256, 2) void attn(
    const unsigned short* __restrict__ Qm, const unsigned short* __restrict__ Km,
    const unsigned short* __restrict__ Vm, unsigned short* __restrict__ Ctx)
{
  constexpr int QB = 128, KVB = 64, NT = S_ / KVB;
  __shared__ unsigned short Qs[QB * DK_];      // 16 KB (swizzled rows)
  __shared__ unsigned short Kd[2][KVB * DK_];  // 2 x 8 KB (swizzled rows)
  __shared__ unsigned short Vd[2][KVB * DK_];  // 2 x 8 KB (subtiled for tr16)
  __shared__ float smA[4][32];                 // per-wave bcast row
  const int tid = threadIdx.x, lane = tid & 63, wave = tid >> 6;
  const int hi = lane >> 5, l31 = lane & 31, g1 = (lane >> 4) & 1;
  const int bh = blockIdx.y, q0 = blockIdx.x * QB;
  const int bq = bh >> 3, hh = bh & 7;
  const char* Qg = (const char*)(Qm + ((size_t)bq * S_ + q0) * D_ + hh * DK_);
  const char* Kg = (const char*)(Km + (size_t)bq * S_ * D_ + hh * DK_);
  const char* Vg = (const char*)(Vm + (size_t)bq * S_ * D_ + hh * DK_);

  // stage 128B-row tile from row-stride-1024B global into swizzled LDS
  auto stageSwz = [&](const char* gbase, unsigned short* lds, int o) {
    int ol = o + lane * 16;
    int row = ol >> 7, off = (ol ^ ((row & 7) << 4)) & 127;
    gld16(gbase + (size_t)row * 1024 + off, (char*)lds + o);
  };
  auto stageVt = [&](const char* gbase, unsigned short* lds, int o) {
    int ol = o + lane * 16;
    int E0 = ol >> 1;
    int st = E0 >> 6, rr = (E0 >> 4) & 3, c0 = E0 & 15;
    int kk = (st >> 2) * 4 + rr, dd = (st & 3) * 16 + c0;
    gld16(gbase + (size_t)kk * 1024 + dd * 2, (char*)lds + o);
  };

  // prologue: stage Q (128 rows) + tile 0
#pragma unroll
  for (int i = 0; i < 4; ++i) stageSwz(Qg, Qs, (wave * 4 + i) * 1024);
#pragma unroll
  for (int i = 0; i < 2; ++i) stageSwz(Kg, Kd[0], (wave * 2 + i) * 1024);
#pragma unroll
  for (int i = 0; i < 2; ++i) stageVt(Vg, Vd[0], (wave * 2 + i) * 1024);
  __syncthreads();

  // Q fragments (B-operand): row = wave*32 + l31, elems d = c*16 + hi*8 + e
  bf16x8 qf[4];
  {
    int row = wave * 32 + l31;
    int rb = row * 128, sw = (row & 7) << 4;
#pragma unroll
    for (int c = 0; c < 4; ++c)
      qf[c] = *(const bf16x8*)((const char*)Qs + ((rb + c * 32 + hi * 16) ^ sw));
  }

  f32x16 oacc[2];
#pragma unroll
  for (int dt = 0; dt < 2; ++dt)
#pragma unroll
    for (int r = 0; r < 16; ++r) oacc[dt][r] = 0.f;
  float m2 = -1e30f, lsum = 0.f;
  constexpr float SCL2 = 0.125f * 1.44269504089f;  // 1/sqrt(DK) * log2(e)

  int cur = 0;
  for (int t = 0; t < NT; ++t) {
    if (t + 1 < NT) {
      const char* Kg1 = Kg + (size_t)(t + 1) * KVB * 1024;
      const char* Vg1 = Vg + (size_t)(t + 1) * KVB * 1024;
#pragma unroll
      for (int i = 0; i < 2; ++i) stageSwz(Kg1, Kd[cur ^ 1], (wave * 2 + i) * 1024);
#pragma unroll
      for (int i = 0; i < 2; ++i) stageVt(Vg1, Vd[cur ^ 1], (wave * 2 + i) * 1024);
    }

    // ---- swapped QK^T: sacc[k2] = K_tile * Q^T (S^T[k][q], q = l31) ----
    f32x16 sacc[2];
#pragma unroll
    for (int k2 = 0; k2 < 2; ++k2)
#pragma unroll
      for (int r = 0; r < 16; ++r) sacc[k2][r] = 0.f;
    __builtin_amdgcn_s_setprio(1);
#pragma unroll
    for (int c = 0; c < 4; ++c) {
#pragma unroll
      for (int k2 = 0; k2 < 2; ++k2) {
        int row = k2 * 32 + l31;
        bf16x8 kf = *(const bf16x8*)((const char*)Kd[cur] +
                     ((row * 128 + c * 32 + hi * 16) ^ ((row & 7) << 4)));
        sacc[k2] = mfma32(kf, qf[c], sacc[k2]);
      }
    }
    __builtin_amdgcn_s_setprio(0);

    // ---- online softmax (unconditional rescale) ----
    float mloc = sacc[0][0];
#pragma unroll
    for (int k2 = 0; k2 < 2; ++k2)
#pragma unroll
      for (int r = 0; r < 16; ++r) mloc = fmaxf(mloc, sacc[k2][r]);
    mloc = fmaxf(mloc, __shfl_xor(mloc, 32));
    float m2n = fmaxf(m2, mloc * SCL2);
    float alpha = __builtin_amdgcn_exp2f(m2 - m2n);
    m2 = m2n;
    float psum = 0.f;
#pragma unroll
    for (int k2 = 0; k2 < 2; ++k2)
#pragma unroll
      for (int r = 0; r < 16; ++r) {
        float p = __builtin_amdgcn_exp2f(fmaf(sacc[k2][r], SCL2, -m2n));
        sacc[k2][r] = p;
        psum += p;
      }
    psum += __shfl_xor(psum, 32);
    lsum = lsum * alpha + psum;

    // broadcast alpha[q] to O-layout lanes via per-wave LDS row
    if (lane < 32) smA[wave][lane] = alpha;
    f32x4 av[4];
#pragma unroll
    for (int s = 0; s < 4; ++s)
      av[s] = *(const f32x4*)&smA[wave][s * 8 + hi * 4];
#pragma unroll
    for (int dt = 0; dt < 2; ++dt)
#pragma unroll
      for (int r = 0; r < 16; ++r) oacc[dt][r] *= av[r >> 2][r & 3];

    // ---- PV: issue V tr-reads, build P-frags while ds in flight ----
    short4v va[4][2][2];
#pragma unroll
    for (int c = 0; c < 4; ++c)
#pragma unroll
      for (int dt = 0; dt < 2; ++dt) {
        int st = 16 * c + 8 * hi + 2 * dt + g1;
        const char* ad = (const char*)Vd[cur] + st * 128 + (lane & 15) * 8;
        va[c][dt][0] = tr16(ad);
        va[c][dt][1] = tr16(ad + 512);
      }
    bf16x8 pfrag[4];
#pragma unroll
    for (int c = 0; c < 4; ++c) {
      const f32x16& P = sacc[c >> 1];
      const int b = (c & 1) * 8;
      unsigned d0 = pkbf(P[b + 0], P[b + 1]);
      unsigned d1 = pkbf(P[b + 2], P[b + 3]);
      unsigned d2 = pkbf(P[b + 4], P[b + 5]);
      unsigned d3 = pkbf(P[b + 6], P[b + 7]);
      pl32swap(d0, d2);
      pl32swap(d1, d3);
      uint4v pi = {d0, d1, d2, d3};
      pfrag[c] = __builtin_bit_cast(bf16x8, pi);
    }
    asm volatile("s_waitcnt lgkmcnt(0)" ::: "memory");
    __builtin_amdgcn_sched_barrier(0);
    __builtin_amdgcn_s_setprio(1);
#pragma unroll
    for (int c = 0; c < 4; ++c)
#pragma unroll
      for (int dt = 0; dt < 2; ++dt) {
        short8v vv = __builtin_shufflevector(va[c][dt][0], va[c][dt][1],
                                             0, 1, 2, 3, 4, 5, 6, 7);
        oacc[dt] = mfma32(pfrag[c], __builtin_bit_cast(bf16x8, vv), oacc[dt]);
      }
    __builtin_amdgcn_s_setprio(0);

    __syncthreads();  // next K/V tile staged; cur safe to overwrite
    cur ^= 1;
  }

  // epilogue: O[q][d], q = (r&3)+8*(r>>2)+4*hi, d = dt*32 + l31
  if (lane < 32) smA[wave][lane] = 1.f / lsum;
  f32x4 iv[4];
#pragma unroll
  for (int s = 0; s < 4; ++s)
    iv[s] = *(const f32x4*)&smA[wave][s * 8 + hi * 4];
#pragma unroll
  for (int dt = 0; dt < 2; ++dt)
#pragma unroll
    for (int r = 0; r < 16; ++r) {
      int qq = (r & 3) + 8 * (r >> 2) + 4 * hi;
      int grow = q0 + wave * 32 + qq;
      int col = hh * 64 + dt * 32 + l31;
      Ctx[((size_t)bq * S_ + grow) * D_ + col] = f2bf(oacc[dt][r] * iv[r >> 2][r & 3]);
    }
}

// ---------------------------------------------------------------------------
extern "C" void kernel_launch(void* const* d_in, const int* in_sizes, int n_in,
                              void* d_out, int out_size, void* d_ws, size_t ws_size,
                              hipStream_t stream) {
  const float* q  = (const float*)d_in[0];
  const float* k  = (const float*)d_in[1];
  const float* v  = (const float*)d_in[2];
  const float* wq = (const float*)d_in[3];
  const float* wk = (const float*)d_in[4];
  const float* wv = (const float*)d_in[5];
  const float* wo = (const float*)d_in[6];
  const float* bo = (const float*)d_in[7];
  float* out = (float*)d_out;

  constexpr size_t NX = (size_t)M_ * D_;
  constexpr size_t NW = (size_t)D_ * D_;
  char* ws = (char*)d_ws;
  unsigned short* Xq  = (unsigned short*)ws; ws += NX * 2;
  unsigned short* Xk  = (unsigned short*)ws; ws += NX * 2;
  unsigned short* Xv  = (unsigned short*)ws; ws += NX * 2;
  unsigned short* Wqb = (unsigned short*)ws; ws += NW * 2;
  unsigned short* Wkb = (unsigned short*)ws; ws += NW * 2;
  unsigned short* Wvb = (unsigned short*)ws; ws += NW * 2;
  unsigned short* Wob = (unsigned short*)ws; ws += NW * 2;
  unsigned short* Qbf = (unsigned short*)ws; ws += NX * 2;
  unsigned short* Kbf = (unsigned short*)ws; ws += NX * 2;
  unsigned short* Vbf = (unsigned short*)ws; ws += NX * 2;
  unsigned short* Cx  = (unsigned short*)ws; ws += NX * 2;

  convert_all<<<2048, 256, 0, stream>>>(q, k, v, wq, wk, wv, wo,
                                        Xq, Xk, Xv, Wqb, Wkb, Wvb, Wob);
  gemm_bt<0><<<dim3(4, 64, 3), 256, 0, stream>>>(
      Xq, Xk, Xv, Wqb, Wkb, Wvb, Qbf, Kbf, Vbf, nullptr, nullptr);
  attn<<<dim3(S_ / 128, B_ * H_), 256, 0, stream>>>(Qbf, Kbf, Vbf, Cx);
  gemm_bt<1><<<dim3(4, 128, 1), 256, 0, stream>>>(
      Cx, nullptr, nullptr, Wob, nullptr, nullptr, nullptr, nullptr, nullptr,
      out, bo);
}

// Round 6
// 200.974 us; speedup vs baseline: 1.0106x; 1.0106x over previous
//
#include <hip/hip_runtime.h>
#include <hip/hip_bf16.h>
#include <stdint.h>

#define DEV __device__ __forceinline__

typedef __attribute__((ext_vector_type(8))) __bf16 bf16x8;
typedef __attribute__((ext_vector_type(4))) float f32x4;
typedef __attribute__((ext_vector_type(16))) float f32x16;
typedef __attribute__((ext_vector_type(4))) short short4v;
typedef __attribute__((ext_vector_type(8))) short short8v;
typedef __attribute__((ext_vector_type(4))) unsigned int uint4v;
typedef __attribute__((ext_vector_type(2))) unsigned int uint2v;

constexpr int B_ = 4, S_ = 2048, D_ = 512, H_ = 8, DK_ = 64;
constexpr int M_ = B_ * S_;   // 8192
constexpr int K_ = D_;        // 512

// RNE float->bf16 (finite inputs only)
DEV unsigned short f2bf(float f) {
  unsigned int u = __builtin_bit_cast(unsigned int, f);
  unsigned int r = (u + 0x7fffu + ((u >> 16) & 1u)) >> 16;
  return (unsigned short)r;
}

DEV void gld16(const void* g, void* l) {
  __builtin_amdgcn_global_load_lds(
      (const __attribute__((address_space(1))) unsigned int*)g,
      (__attribute__((address_space(3))) unsigned int*)l, 16, 0, 0);
}

DEV f32x4 mfma16(bf16x8 a, bf16x8 b, f32x4 c) {
  return __builtin_amdgcn_mfma_f32_16x16x32_bf16(a, b, c, 0, 0, 0);
}
DEV f32x16 mfma32(bf16x8 a, bf16x8 b, f32x16 c) {
  return __builtin_amdgcn_mfma_f32_32x32x16_bf16(a, b, c, 0, 0, 0);
}

// ds_read_b64_tr_b16: 16-lane group reads a 128B window (4x16 bf16 subtile),
// lane m of group gets column m.
DEV short4v tr16(const void* p) {
  short4v d;
  asm volatile("ds_read_b64_tr_b16 %0, %1"
               : "=v"(d)
               : "v"((const __attribute__((address_space(3))) char*)p));
  return d;
}

DEV unsigned pkbf(float a, float b) {  // dword = {lo: bf16(a), hi: bf16(b)}
  unsigned r;
  asm("v_cvt_pk_bf16_f32 %0, %1, %2" : "=v"(r) : "v"(a), "v"(b));
  return r;
}

DEV void pl32swap(unsigned& a, unsigned& b) {  // a[32:63] <-> b[0:31]
  asm volatile("v_permlane32_swap_b32 %0, %1" : "+v"(a), "+v"(b));
}

// ---------------------------------------------------------------------------
// Kernel 1: convert the 4 weight matrices fp32 -> bf16 (tiny: 4 MB read)
// ---------------------------------------------------------------------------
__global__ __launch_bounds__(256) void convert_w(
    const float* __restrict__ w0, const float* __restrict__ w1,
    const float* __restrict__ w2, const float* __restrict__ w3,
    unsigned short* __restrict__ o0, unsigned short* __restrict__ o1,
    unsigned short* __restrict__ o2, unsigned short* __restrict__ o3)
{
  int u = blockIdx.x * 256 + threadIdx.x;       // 0 .. 4*65536-1
  int t = u >> 16, off = (u & 65535) * 4;
  const float* src = (t == 0) ? w0 : (t == 1) ? w1 : (t == 2) ? w2 : w3;
  unsigned short* dst = (t == 0) ? o0 : (t == 1) ? o1 : (t == 2) ? o2 : o3;
  float4 f = *(const float4*)(src + off);
  short4v o;
  o.x = (short)f2bf(f.x); o.y = (short)f2bf(f.y);
  o.z = (short)f2bf(f.z); o.w = (short)f2bf(f.w);
  *(short4v*)(dst + off) = o;
}

// ---------------------------------------------------------------------------
// Kernel 2a: fused QKV projections. A = raw fp32 input (reg-staged + inline
// cvt to bf16, T14 split: next-tile loads issued under current MFMA);
// W = pre-converted bf16 via gld16. XOR-swizzled LDS (byte-identical image to
// the validated round-5 path). BM=128, BN=128, BK=64; single-buffer 2-barrier.
// Out: bf16 [M,512].
// ---------------------------------------------------------------------------
__global__ __launch_bounds__(256, 3) void gemm_qkv(
    const float* __restrict__ A0, const float* __restrict__ A1,
    const float* __restrict__ A2,
    const unsigned short* __restrict__ W0, const unsigned short* __restrict__ W1,
    const unsigned short* __restrict__ W2,
    unsigned short* __restrict__ O0, unsigned short* __restrict__ O1,
    unsigned short* __restrict__ O2)
{
  constexpr int BM = 128, BN = 128, BK = 64, NKT = K_ / BK;
  __shared__ unsigned short As[BM * BK];  // 16 KB
  __shared__ unsigned short Bs[BN * BK];  // 16 KB
  const int tid = threadIdx.x, lane = tid & 63, wave = tid >> 6;
  const int z = blockIdx.z;
  const float* A = (z == 0) ? A0 : (z == 1 ? A1 : A2);
  const unsigned short* W = (z == 0) ? W0 : (z == 1 ? W1 : W2);
  unsigned short* outH = (z == 0) ? O0 : (z == 1 ? O1 : O2);
  const int bn0 = blockIdx.x * BN, bm0 = blockIdx.y * BM;
  const int wr = (wave >> 1) * 64, wc = (wave & 1) * 64;
  const int frow = lane & 15, fk16 = (lane >> 4) * 16;

  // A staging assignment: thread -> (row, 32-elem half-row)
  const int srow = tid >> 1, scol = (tid & 1) * 32;
  const float* asrc = A + (size_t)(bm0 + srow) * K_ + scol;
  const int abase = srow * 128 + scol * 2, asw = (srow & 7) << 4;

  // hoisted W staging pointers (kt term added in-loop)
  const char* srcB[4];
  int dstB[4];
#pragma unroll
  for (int i = 0; i < 4; ++i) {
    int o = (wave * 4 + i) * 1024;
    int ol = o + lane * 16;
    int row = ol >> 7, off = (ol ^ ((row & 7) << 4)) & 127;
    srcB[i] = (const char*)W + (size_t)(bn0 + row) * (K_ * 2) + off;
    dstB[i] = o;
  }

  f32x4 acc[4][4];
#pragma unroll
  for (int i = 0; i < 4; ++i)
#pragma unroll
    for (int j = 0; j < 4; ++j)
#pragma unroll
      for (int r = 0; r < 4; ++r) acc[i][j][r] = 0.f;

  // preload A(0) into regs
  float4 xv[8];
#pragma unroll
  for (int j = 0; j < 8; ++j) xv[j] = *(const float4*)(asrc + j * 4);

  for (int kt = 0; kt < NKT; ++kt) {
    __syncthreads();  // all waves done reading As/Bs of kt-1
    // write A(kt): cvt staged regs -> swizzled LDS
    {
      unsigned dw[16];
#pragma unroll
      for (int j = 0; j < 8; ++j) {
        dw[2 * j]     = pkbf(xv[j].x, xv[j].y);
        dw[2 * j + 1] = pkbf(xv[j].z, xv[j].w);
      }
#pragma unroll
      for (int c = 0; c < 4; ++c) {
        uint4v q = {dw[4 * c], dw[4 * c + 1], dw[4 * c + 2], dw[4 * c + 3]};
        *(uint4v*)((char*)As + ((abase + c * 16) ^ asw)) = q;
      }
    }
#pragma unroll
    for (int i = 0; i < 4; ++i) gld16(srcB[i] + kt * 128, (char*)Bs + dstB[i]);
    __syncthreads();  // staged data visible (vm+lgkm drained)
    // issue A(kt+1) loads; latency hides under compute(kt)
    if (kt + 1 < NKT) {
#pragma unroll
      for (int j = 0; j < 8; ++j)
        xv[j] = *(const float4*)(asrc + (kt + 1) * 64 + j * 4);
    }
#pragma unroll
    for (int kc = 0; kc < 2; ++kc) {
      bf16x8 a[4], b[4];
#pragma unroll
      for (int i = 0; i < 4; ++i) {
        int row = wr + i * 16 + frow;
        a[i] = *(const bf16x8*)((const char*)As +
                ((row * 128 + kc * 64 + fk16) ^ ((row & 7) << 4)));
      }
#pragma unroll
      for (int j = 0; j < 4; ++j) {
        int row = wc + j * 16 + frow;
        b[j] = *(const bf16x8*)((const char*)Bs +
                ((row * 128 + kc * 64 + fk16) ^ ((row & 7) << 4)));
      }
      __builtin_amdgcn_s_setprio(1);
#pragma unroll
      for (int i = 0; i < 4; ++i)
#pragma unroll
        for (int j = 0; j < 4; ++j)
          acc[i][j] = mfma16(a[i], b[j], acc[i][j]);
      __builtin_amdgcn_s_setprio(0);
    }
  }

  // epilogue: C/D layout col = lane&15, row = (lane>>4)*4 + reg
  const int r0 = (lane >> 4) * 4, cn = lane & 15;
#pragma unroll
  for (int i = 0; i < 4; ++i)
#pragma unroll
    for (int j = 0; j < 4; ++j)
#pragma unroll
      for (int r = 0; r < 4; ++r) {
        int gm = bm0 + wr + i * 16 + r0 + r;
        int gn = bn0 + wc + j * 16 + cn;
        outH[(size_t)gm * D_ + gn] = f2bf(acc[i][j][r]);
      }
}

// ---------------------------------------------------------------------------
// Kernel 2b: output projection (round-5 validated MODE1, unchanged).
// A = Cx bf16 gld16; W = Wob bf16 gld16. BM=64, BN=128; fp32 + bias out.
// ---------------------------------------------------------------------------
__global__ __launch_bounds__(256, 4) void gemm_out(
    const unsigned short* __restrict__ A, const unsigned short* __restrict__ W,
    float* __restrict__ outF, const float* __restrict__ bias)
{
  constexpr int BM = 64, BN = 128, BK = 64, NKT = K_ / BK, AFR = 2;
  __shared__ unsigned short As[BM * BK];  // 8 KB
  __shared__ unsigned short Bs[BN * BK];  // 16 KB
  const int tid = threadIdx.x, lane = tid & 63, wave = tid >> 6;
  const int bn0 = blockIdx.x * BN, bm0 = blockIdx.y * BM;
  const int wr = (wave >> 1) * 32, wc = (wave & 1) * 64;
  const int frow = lane & 15, fk16 = (lane >> 4) * 16;

  const char* srcA[AFR];
  int dstA[AFR];
#pragma unroll
  for (int i = 0; i < AFR; ++i) {
    int o = (wave * AFR + i) * 1024;
    int ol = o + lane * 16;
    int row = ol >> 7, off = (ol ^ ((row & 7) << 4)) & 127;
    srcA[i] = (const char*)A + (size_t)(bm0 + row) * (K_ * 2) + off;
    dstA[i] = o;
  }
  const char* srcB[4];
  int dstB[4];
#pragma unroll
  for (int i = 0; i < 4; ++i) {
    int o = (wave * 4 + i) * 1024;
    int ol = o + lane * 16;
    int row = ol >> 7, off = (ol ^ ((row & 7) << 4)) & 127;
    srcB[i] = (const char*)W + (size_t)(bn0 + row) * (K_ * 2) + off;
    dstB[i] = o;
  }

  f32x4 acc[AFR][4];
#pragma unroll
  for (int i = 0; i < AFR; ++i)
#pragma unroll
    for (int j = 0; j < 4; ++j)
#pragma unroll
      for (int r = 0; r < 4; ++r) acc[i][j][r] = 0.f;

  for (int kt = 0; kt < NKT; ++kt) {
    __syncthreads();
#pragma unroll
    for (int i = 0; i < AFR; ++i) gld16(srcA[i] + kt * 128, (char*)As + dstA[i]);
#pragma unroll
    for (int i = 0; i < 4; ++i)   gld16(srcB[i] + kt * 128, (char*)Bs + dstB[i]);
    __syncthreads();
#pragma unroll
    for (int kc = 0; kc < 2; ++kc) {
      bf16x8 a[AFR], b[4];
#pragma unroll
      for (int i = 0; i < AFR; ++i) {
        int row = wr + i * 16 + frow;
        a[i] = *(const bf16x8*)((const char*)As +
                ((row * 128 + kc * 64 + fk16) ^ ((row & 7) << 4)));
      }
#pragma unroll
      for (int j = 0; j < 4; ++j) {
        int row = wc + j * 16 + frow;
        b[j] = *(const bf16x8*)((const char*)Bs +
                ((row * 128 + kc * 64 + fk16) ^ ((row & 7) << 4)));
      }
      __builtin_amdgcn_s_setprio(1);
#pragma unroll
      for (int i = 0; i < AFR; ++i)
#pragma unroll
        for (int j = 0; j < 4; ++j)
          acc[i][j] = mfma16(a[i], b[j], acc[i][j]);
      __builtin_amdgcn_s_setprio(0);
    }
  }

  const int r0 = (lane >> 4) * 4, cn = lane & 15;
  float bv[4];
#pragma unroll
  for (int j = 0; j < 4; ++j) bv[j] = bias[bn0 + wc + j * 16 + cn];
#pragma unroll
  for (int i = 0; i < AFR; ++i)
#pragma unroll
    for (int j = 0; j < 4; ++j)
#pragma unroll
      for (int r = 0; r < 4; ++r) {
        int gm = bm0 + wr + i * 16 + r0 + r;
        int gn = bn0 + wc + j * 16 + cn;
        outF[(size_t)gm * D_ + gn] = acc[i][j][r] + bv[j];
      }
}

// ---------------------------------------------------------------------------
// Kernel 3: flash attention. Round-5 validated core PLUS:
//  - PV operand swap: oacc = mfma32(vv, pfrag, oacc) computes O^T
//    (rows=d on regs, cols=q on lane) -> alpha/lsum live in the right lane,
//    smA broadcast deleted; packed 8B Ctx stores.
//  - att[2]-lite: PV(t-1) issued right after QK^T(t); softmax(t) VALU
//    overlaps PV MFMA. pfrag/va zero-init; pending PV after loop.
// ---------------------------------------------------------------------------
__global__ __launch_bounds__(256, 2) void attn(
    const unsigned short* __restrict__ Qm, const unsigned short* __restrict__ Km,
    const unsigned short* __restrict__ Vm, unsigned short* __restrict__ Ctx)
{
  constexpr int QB = 128, KVB = 64, NT = S_ / KVB;
  __shared__ unsigned short Qs[QB * DK_];      // 16 KB (swizzled rows)
  __shared__ unsigned short Kd[2][KVB * DK_];  // 2 x 8 KB (swizzled rows)
  __shared__ unsigned short Vd[2][KVB * DK_];  // 2 x 8 KB (subtiled for tr16)
  const int tid = threadIdx.x, lane = tid & 63, wave = tid >> 6;
  const int hi = lane >> 5, l31 = lane & 31, g1 = (lane >> 4) & 1;
  const int bh = blockIdx.y, q0 = blockIdx.x * QB;
  const int bq = bh >> 3, hh = bh & 7;
  const char* Qg = (const char*)(Qm + ((size_t)bq * S_ + q0) * D_ + hh * DK_);
  const char* Kg = (const char*)(Km + (size_t)bq * S_ * D_ + hh * DK_);
  const char* Vg = (const char*)(Vm + (size_t)bq * S_ * D_ + hh * DK_);

  auto stageSwz = [&](const char* gbase, unsigned short* lds, int o) {
    int ol = o + lane * 16;
    int row = ol >> 7, off = (ol ^ ((row & 7) << 4)) & 127;
    gld16(gbase + (size_t)row * 1024 + off, (char*)lds + o);
  };
  auto stageVt = [&](const char* gbase, unsigned short* lds, int o) {
    int ol = o + lane * 16;
    int E0 = ol >> 1;
    int st = E0 >> 6, rr = (E0 >> 4) & 3, c0 = E0 & 15;
    int kk = (st >> 2) * 4 + rr, dd = (st & 3) * 16 + c0;
    gld16(gbase + (size_t)kk * 1024 + dd * 2, (char*)lds + o);
  };

  // prologue: stage Q (128 rows) + tile 0
#pragma unroll
  for (int i = 0; i < 4; ++i) stageSwz(Qg, Qs, (wave * 4 + i) * 1024);
#pragma unroll
  for (int i = 0; i < 2; ++i) stageSwz(Kg, Kd[0], (wave * 2 + i) * 1024);
#pragma unroll
  for (int i = 0; i < 2; ++i) stageVt(Vg, Vd[0], (wave * 2 + i) * 1024);
  __syncthreads();

  // Q fragments (B-operand): row = wave*32 + l31, elems d = c*16 + hi*8 + e
  bf16x8 qf[4];
  {
    int row = wave * 32 + l31;
    int rb = row * 128, sw = (row & 7) << 4;
#pragma unroll
    for (int c = 0; c < 4; ++c)
      qf[c] = *(const bf16x8*)((const char*)Qs + ((rb + c * 32 + hi * 16) ^ sw));
  }

  f32x16 oacc[2];
#pragma unroll
  for (int dt = 0; dt < 2; ++dt)
#pragma unroll
    for (int r = 0; r < 16; ++r) oacc[dt][r] = 0.f;
  float m2 = -1e30f, lsum = 0.f;
  constexpr float SCL2 = 0.125f * 1.44269504089f;  // 1/sqrt(DK) * log2(e)

  // att[2] carried state (tile t-1): zero so iter 0's PV adds nothing
  short4v va[4][2][2];
  bf16x8 pfrag[4];
#pragma unroll
  for (int c = 0; c < 4; ++c) {
#pragma unroll
    for (int dt = 0; dt < 2; ++dt) {
      va[c][dt][0] = short4v{0, 0, 0, 0};
      va[c][dt][1] = short4v{0, 0, 0, 0};
    }
    uint4v zz = {0u, 0u, 0u, 0u};
    pfrag[c] = __builtin_bit_cast(bf16x8, zz);
  }

  int cur = 0;
  for (int t = 0; t < NT; ++t) {
    if (t + 1 < NT) {
      const char* Kg1 = Kg + (size_t)(t + 1) * KVB * 1024;
      const char* Vg1 = Vg + (size_t)(t + 1) * KVB * 1024;
#pragma unroll
      for (int i = 0; i < 2; ++i) stageSwz(Kg1, Kd[cur ^ 1], (wave * 2 + i) * 1024);
#pragma unroll
      for (int i = 0; i < 2; ++i) stageVt(Vg1, Vd[cur ^ 1], (wave * 2 + i) * 1024);
    }

    // ---- swapped QK^T: sacc[k2] = K_tile * Q^T (S^T[k][q], q = l31) ----
    f32x16 sacc[2];
#pragma unroll
    for (int k2 = 0; k2 < 2; ++k2)
#pragma unroll
      for (int r = 0; r < 16; ++r) sacc[k2][r] = 0.f;
    __builtin_amdgcn_s_setprio(1);
#pragma unroll
    for (int c = 0; c < 4; ++c) {
#pragma unroll
      for (int k2 = 0; k2 < 2; ++k2) {
        int row = k2 * 32 + l31;
        bf16x8 kf = *(const bf16x8*)((const char*)Kd[cur] +
                     ((row * 128 + c * 32 + hi * 16) ^ ((row & 7) << 4)));
        sacc[k2] = mfma32(kf, qf[c], sacc[k2]);
      }
    }
    // ---- PV(t-1): O^T += V^T * P  (args swapped vs round 5) ----
#pragma unroll
    for (int c = 0; c < 4; ++c)
#pragma unroll
      for (int dt = 0; dt < 2; ++dt) {
        short8v vv = __builtin_shufflevector(va[c][dt][0], va[c][dt][1],
                                             0, 1, 2, 3, 4, 5, 6, 7);
        oacc[dt] = mfma32(__builtin_bit_cast(bf16x8, vv), pfrag[c], oacc[dt]);
      }
    __builtin_amdgcn_s_setprio(0);

    // ---- online softmax(t): VALU, overlaps PV(t-1) MFMA above ----
    float mloc = sacc[0][0];
#pragma unroll
    for (int k2 = 0; k2 < 2; ++k2)
#pragma unroll
      for (int r = 0; r < 16; ++r) mloc = fmaxf(mloc, sacc[k2][r]);
    mloc = fmaxf(mloc, __shfl_xor(mloc, 32));
    float m2n = fmaxf(m2, mloc * SCL2);
    float alpha = __builtin_amdgcn_exp2f(m2 - m2n);
    m2 = m2n;
    float psum = 0.f;
#pragma unroll
    for (int k2 = 0; k2 < 2; ++k2)
#pragma unroll
      for (int r = 0; r < 16; ++r) {
        float p = __builtin_amdgcn_exp2f(fmaf(sacc[k2][r], SCL2, -m2n));
        sacc[k2][r] = p;
        psum += p;
      }
    psum += __shfl_xor(psum, 32);
    lsum = lsum * alpha + psum;

    // rescale O^T: cols = q = own l31 -> scalar multiply, no broadcast
#pragma unroll
    for (int dt = 0; dt < 2; ++dt)
#pragma unroll
      for (int r = 0; r < 16; ++r) oacc[dt][r] *= alpha;

    // ---- va(t) tr-reads + pfrag(t) build (consumed next iter) ----
#pragma unroll
    for (int c = 0; c < 4; ++c)
#pragma unroll
      for (int dt = 0; dt < 2; ++dt) {
        int st = 16 * c + 8 * hi + 2 * dt + g1;
        const char* ad = (const char*)Vd[cur] + st * 128 + (lane & 15) * 8;
        va[c][dt][0] = tr16(ad);
        va[c][dt][1] = tr16(ad + 512);
      }
#pragma unroll
    for (int c = 0; c < 4; ++c) {
      const f32x16& P = sacc[c >> 1];
      const int b = (c & 1) * 8;
      unsigned d0 = pkbf(P[b + 0], P[b + 1]);
      unsigned d1 = pkbf(P[b + 2], P[b + 3]);
      unsigned d2 = pkbf(P[b + 4], P[b + 5]);
      unsigned d3 = pkbf(P[b + 6], P[b + 7]);
      pl32swap(d0, d2);
      pl32swap(d1, d3);
      uint4v pi = {d0, d1, d2, d3};
      pfrag[c] = __builtin_bit_cast(bf16x8, pi);
    }

    __syncthreads();  // next K/V staged; va tr-reads drained; cur swap safe
    cur ^= 1;
  }

  // pending PV(NT-1)
  __builtin_amdgcn_s_setprio(1);
#pragma unroll
  for (int c = 0; c < 4; ++c)
#pragma unroll
    for (int dt = 0; dt < 2; ++dt) {
      short8v vv = __builtin_shufflevector(va[c][dt][0], va[c][dt][1],
                                           0, 1, 2, 3, 4, 5, 6, 7);
      oacc[dt] = mfma32(__builtin_bit_cast(bf16x8, vv), pfrag[c], oacc[dt]);
    }
  __builtin_amdgcn_s_setprio(0);

  // epilogue: O^T regs walk d; q = l31. d = dt*32 + 8g + 4hi + j (j=0..3)
  const float inv = 1.f / lsum;
  unsigned short* crow =
      Ctx + ((size_t)bq * S_ + q0 + wave * 32 + l31) * D_ + hh * DK_;
#pragma unroll
  for (int dt = 0; dt < 2; ++dt)
#pragma unroll
    for (int g = 0; g < 4; ++g) {
      uint2v pk;
      pk.x = pkbf(oacc[dt][4 * g + 0] * inv, oacc[dt][4 * g + 1] * inv);
      pk.y = pkbf(oacc[dt][4 * g + 2] * inv, oacc[dt][4 * g + 3] * inv);
      *(uint2v*)(crow + dt * 32 + 8 * g + 4 * hi) = pk;
    }
}

// ---------------------------------------------------------------------------
extern "C" void kernel_launch(void* const* d_in, const int* in_sizes, int n_in,
                              void* d_out, int out_size, void* d_ws, size_t ws_size,
                              hipStream_t stream) {
  const float* q  = (const float*)d_in[0];
  const float* k  = (const float*)d_in[1];
  const float* v  = (const float*)d_in[2];
  const float* wq = (const float*)d_in[3];
  const float* wk = (const float*)d_in[4];
  const float* wv = (const float*)d_in[5];
  const float* wo = (const float*)d_in[6];
  const float* bo = (const float*)d_in[7];
  float* out = (float*)d_out;

  constexpr size_t NX = (size_t)M_ * D_;
  constexpr size_t NW = (size_t)D_ * D_;
  char* ws = (char*)d_ws;
  unsigned short* Wqb = (unsigned short*)ws; ws += NW * 2;
  unsigned short* Wkb = (unsigned short*)ws; ws += NW * 2;
  unsigned short* Wvb = (unsigned short*)ws; ws += NW * 2;
  unsigned short* Wob = (unsigned short*)ws; ws += NW * 2;
  unsigned short* Qbf = (unsigned short*)ws; ws += NX * 2;
  unsigned short* Kbf = (unsigned short*)ws; ws += NX * 2;
  unsigned short* Vbf = (unsigned short*)ws; ws += NX * 2;
  unsigned short* Cx  = (unsigned short*)ws; ws += NX * 2;

  convert_w<<<1024, 256, 0, stream>>>(wq, wk, wv, wo, Wqb, Wkb, Wvb, Wob);
  gemm_qkv<<<dim3(4, 64, 3), 256, 0, stream>>>(
      q, k, v, Wqb, Wkb, Wvb, Qbf, Kbf, Vbf);
  attn<<<dim3(S_ / 128, B_ * H_), 256, 0, stream>>>(Qbf, Kbf, Vbf, Cx);
  gemm_out<<<dim3(4, 128), 256, 0, stream>>>(Cx, Wob, out, bo);
}

// Round 8
// 199.344 us; speedup vs baseline: 1.0189x; 1.0082x over previous
//
#include <hip/hip_runtime.h>
#include <hip/hip_bf16.h>
#include <stdint.h>

#define DEV __device__ __forceinline__

typedef __attribute__((ext_vector_type(8))) __bf16 bf16x8;
typedef __attribute__((ext_vector_type(4))) float f32x4;
typedef __attribute__((ext_vector_type(16))) float f32x16;
typedef __attribute__((ext_vector_type(4))) short short4v;
typedef __attribute__((ext_vector_type(8))) short short8v;
typedef __attribute__((ext_vector_type(4))) unsigned int uint4v;
typedef __attribute__((ext_vector_type(2))) unsigned int uint2v;

constexpr int B_ = 4, S_ = 2048, D_ = 512, H_ = 8, DK_ = 64;
constexpr int M_ = B_ * S_;   // 8192
constexpr int K_ = D_;        // 512

// RNE float->bf16 (finite inputs only)
DEV unsigned short f2bf(float f) {
  unsigned int u = __builtin_bit_cast(unsigned int, f);
  unsigned int r = (u + 0x7fffu + ((u >> 16) & 1u)) >> 16;
  return (unsigned short)r;
}

DEV void gld16(const void* g, void* l) {
  __builtin_amdgcn_global_load_lds(
      (const __attribute__((address_space(1))) unsigned int*)g,
      (__attribute__((address_space(3))) unsigned int*)l, 16, 0, 0);
}

DEV f32x4 mfma16(bf16x8 a, bf16x8 b, f32x4 c) {
  return __builtin_amdgcn_mfma_f32_16x16x32_bf16(a, b, c, 0, 0, 0);
}
DEV f32x16 mfma32(bf16x8 a, bf16x8 b, f32x16 c) {
  return __builtin_amdgcn_mfma_f32_32x32x16_bf16(a, b, c, 0, 0, 0);
}

// ds_read_b64_tr_b16 with compile-time additive offset (m162: offset:N == addr+N)
template <int OFF>
DEV short4v tr16o(const void* p) {
  short4v d;
  asm volatile("ds_read_b64_tr_b16 %0, %1 offset:%2"
               : "=v"(d)
               : "v"((const __attribute__((address_space(3))) char*)p), "i"(OFF));
  return d;
}

DEV unsigned pkbf(float a, float b) {  // dword = {lo: bf16(a), hi: bf16(b)}
  unsigned r;
  asm("v_cvt_pk_bf16_f32 %0, %1, %2" : "=v"(r) : "v"(a), "v"(b));
  return r;
}

DEV void pl32swap(unsigned& a, unsigned& b) {  // a[32:63] <-> b[0:31]; a,b MUST be distinct values
  asm volatile("v_permlane32_swap_b32 %0, %1" : "+v"(a), "+v"(b));
}

// ---------------------------------------------------------------------------
// Kernel 1: convert the 4 weight matrices fp32 -> bf16 (tiny: 4 MB read)
// ---------------------------------------------------------------------------
__global__ __launch_bounds__(256) void convert_w(
    const float* __restrict__ w0, const float* __restrict__ w1,
    const float* __restrict__ w2, const float* __restrict__ w3,
    unsigned short* __restrict__ o0, unsigned short* __restrict__ o1,
    unsigned short* __restrict__ o2, unsigned short* __restrict__ o3)
{
  int u = blockIdx.x * 256 + threadIdx.x;       // 0 .. 4*65536-1
  int t = u >> 16, off = (u & 65535) * 4;
  const float* src = (t == 0) ? w0 : (t == 1) ? w1 : (t == 2) ? w2 : w3;
  unsigned short* dst = (t == 0) ? o0 : (t == 1) ? o1 : (t == 2) ? o2 : o3;
  float4 f = *(const float4*)(src + off);
  short4v o;
  o.x = (short)f2bf(f.x); o.y = (short)f2bf(f.y);
  o.z = (short)f2bf(f.z); o.w = (short)f2bf(f.w);
  *(short4v*)(dst + off) = o;
}

// ---------------------------------------------------------------------------
// Kernel 2a: fused QKV projections (round-6 validated, unchanged).
// ---------------------------------------------------------------------------
__global__ __launch_bounds__(256, 3) void gemm_qkv(
    const float* __restrict__ A0, const float* __restrict__ A1,
    const float* __restrict__ A2,
    const unsigned short* __restrict__ W0, const unsigned short* __restrict__ W1,
    const unsigned short* __restrict__ W2,
    unsigned short* __restrict__ O0, unsigned short* __restrict__ O1,
    unsigned short* __restrict__ O2)
{
  constexpr int BM = 128, BN = 128, BK = 64, NKT = K_ / BK;
  __shared__ unsigned short As[BM * BK];  // 16 KB
  __shared__ unsigned short Bs[BN * BK];  // 16 KB
  const int tid = threadIdx.x, lane = tid & 63, wave = tid >> 6;
  const int z = blockIdx.z;
  const float* A = (z == 0) ? A0 : (z == 1 ? A1 : A2);
  const unsigned short* W = (z == 0) ? W0 : (z == 1 ? W1 : W2);
  unsigned short* outH = (z == 0) ? O0 : (z == 1 ? O1 : O2);
  const int bn0 = blockIdx.x * BN, bm0 = blockIdx.y * BM;
  const int wr = (wave >> 1) * 64, wc = (wave & 1) * 64;
  const int frow = lane & 15, fk16 = (lane >> 4) * 16;

  const int srow = tid >> 1, scol = (tid & 1) * 32;
  const float* asrc = A + (size_t)(bm0 + srow) * K_ + scol;
  const int abase = srow * 128 + scol * 2, asw = (srow & 7) << 4;

  const char* srcB[4];
  int dstB[4];
#pragma unroll
  for (int i = 0; i < 4; ++i) {
    int o = (wave * 4 + i) * 1024;
    int ol = o + lane * 16;
    int row = ol >> 7, off = (ol ^ ((row & 7) << 4)) & 127;
    srcB[i] = (const char*)W + (size_t)(bn0 + row) * (K_ * 2) + off;
    dstB[i] = o;
  }

  f32x4 acc[4][4];
#pragma unroll
  for (int i = 0; i < 4; ++i)
#pragma unroll
    for (int j = 0; j < 4; ++j)
#pragma unroll
      for (int r = 0; r < 4; ++r) acc[i][j][r] = 0.f;

  float4 xv[8];
#pragma unroll
  for (int j = 0; j < 8; ++j) xv[j] = *(const float4*)(asrc + j * 4);

  for (int kt = 0; kt < NKT; ++kt) {
    __syncthreads();
    {
      unsigned dw[16];
#pragma unroll
      for (int j = 0; j < 8; ++j) {
        dw[2 * j]     = pkbf(xv[j].x, xv[j].y);
        dw[2 * j + 1] = pkbf(xv[j].z, xv[j].w);
      }
#pragma unroll
      for (int c = 0; c < 4; ++c) {
        uint4v q = {dw[4 * c], dw[4 * c + 1], dw[4 * c + 2], dw[4 * c + 3]};
        *(uint4v*)((char*)As + ((abase + c * 16) ^ asw)) = q;
      }
    }
#pragma unroll
    for (int i = 0; i < 4; ++i) gld16(srcB[i] + kt * 128, (char*)Bs + dstB[i]);
    __syncthreads();
    if (kt + 1 < NKT) {
#pragma unroll
      for (int j = 0; j < 8; ++j)
        xv[j] = *(const float4*)(asrc + (kt + 1) * 64 + j * 4);
    }
#pragma unroll
    for (int kc = 0; kc < 2; ++kc) {
      bf16x8 a[4], b[4];
#pragma unroll
      for (int i = 0; i < 4; ++i) {
        int row = wr + i * 16 + frow;
        a[i] = *(const bf16x8*)((const char*)As +
                ((row * 128 + kc * 64 + fk16) ^ ((row & 7) << 4)));
      }
#pragma unroll
      for (int j = 0; j < 4; ++j) {
        int row = wc + j * 16 + frow;
        b[j] = *(const bf16x8*)((const char*)Bs +
                ((row * 128 + kc * 64 + fk16) ^ ((row & 7) << 4)));
      }
      __builtin_amdgcn_s_setprio(1);
#pragma unroll
      for (int i = 0; i < 4; ++i)
#pragma unroll
        for (int j = 0; j < 4; ++j)
          acc[i][j] = mfma16(a[i], b[j], acc[i][j]);
      __builtin_amdgcn_s_setprio(0);
    }
  }

  const int r0 = (lane >> 4) * 4, cn = lane & 15;
#pragma unroll
  for (int i = 0; i < 4; ++i)
#pragma unroll
    for (int j = 0; j < 4; ++j)
#pragma unroll
      for (int r = 0; r < 4; ++r) {
        int gm = bm0 + wr + i * 16 + r0 + r;
        int gn = bn0 + wc + j * 16 + cn;
        outH[(size_t)gm * D_ + gn] = f2bf(acc[i][j][r]);
      }
}

// ---------------------------------------------------------------------------
// Kernel 2b: output projection (round-6 validated, unchanged).
// ---------------------------------------------------------------------------
__global__ __launch_bounds__(256, 4) void gemm_out(
    const unsigned short* __restrict__ A, const unsigned short* __restrict__ W,
    float* __restrict__ outF, const float* __restrict__ bias)
{
  constexpr int BM = 64, BN = 128, BK = 64, NKT = K_ / BK, AFR = 2;
  __shared__ unsigned short As[BM * BK];  // 8 KB
  __shared__ unsigned short Bs[BN * BK];  // 16 KB
  const int tid = threadIdx.x, lane = tid & 63, wave = tid >> 6;
  const int bn0 = blockIdx.x * BN, bm0 = blockIdx.y * BM;
  const int wr = (wave >> 1) * 32, wc = (wave & 1) * 64;
  const int frow = lane & 15, fk16 = (lane >> 4) * 16;

  const char* srcA[AFR];
  int dstA[AFR];
#pragma unroll
  for (int i = 0; i < AFR; ++i) {
    int o = (wave * AFR + i) * 1024;
    int ol = o + lane * 16;
    int row = ol >> 7, off = (ol ^ ((row & 7) << 4)) & 127;
    srcA[i] = (const char*)A + (size_t)(bm0 + row) * (K_ * 2) + off;
    dstA[i] = o;
  }
  const char* srcB[4];
  int dstB[4];
#pragma unroll
  for (int i = 0; i < 4; ++i) {
    int o = (wave * 4 + i) * 1024;
    int ol = o + lane * 16;
    int row = ol >> 7, off = (ol ^ ((row & 7) << 4)) & 127;
    srcB[i] = (const char*)W + (size_t)(bn0 + row) * (K_ * 2) + off;
    dstB[i] = o;
  }

  f32x4 acc[AFR][4];
#pragma unroll
  for (int i = 0; i < AFR; ++i)
#pragma unroll
    for (int j = 0; j < 4; ++j)
#pragma unroll
      for (int r = 0; r < 4; ++r) acc[i][j][r] = 0.f;

  for (int kt = 0; kt < NKT; ++kt) {
    __syncthreads();
#pragma unroll
    for (int i = 0; i < AFR; ++i) gld16(srcA[i] + kt * 128, (char*)As + dstA[i]);
#pragma unroll
    for (int i = 0; i < 4; ++i)   gld16(srcB[i] + kt * 128, (char*)Bs + dstB[i]);
    __syncthreads();
#pragma unroll
    for (int kc = 0; kc < 2; ++kc) {
      bf16x8 a[AFR], b[4];
#pragma unroll
      for (int i = 0; i < AFR; ++i) {
        int row = wr + i * 16 + frow;
        a[i] = *(const bf16x8*)((const char*)As +
                ((row * 128 + kc * 64 + fk16) ^ ((row & 7) << 4)));
      }
#pragma unroll
      for (int j = 0; j < 4; ++j) {
        int row = wc + j * 16 + frow;
        b[j] = *(const bf16x8*)((const char*)Bs +
                ((row * 128 + kc * 64 + fk16) ^ ((row & 7) << 4)));
      }
      __builtin_amdgcn_s_setprio(1);
#pragma unroll
      for (int i = 0; i < AFR; ++i)
#pragma unroll
        for (int j = 0; j < 4; ++j)
          acc[i][j] = mfma16(a[i], b[j], acc[i][j]);
      __builtin_amdgcn_s_setprio(0);
    }
  }

  const int r0 = (lane >> 4) * 4, cn = lane & 15;
  float bv[4];
#pragma unroll
  for (int j = 0; j < 4; ++j) bv[j] = bias[bn0 + wc + j * 16 + cn];
#pragma unroll
  for (int i = 0; i < AFR; ++i)
#pragma unroll
    for (int j = 0; j < 4; ++j)
#pragma unroll
      for (int r = 0; r < 4; ++r) {
        int gm = bm0 + wr + i * 16 + r0 + r;
        int gn = bn0 + wc + j * 16 + cn;
        outF[(size_t)gm * D_ + gn] = acc[i][j][r] + bv[j];
      }
}

// ---------------------------------------------------------------------------
// Kernel 3: flash attention. Round-6 core PLUS:
//  - manual 2x unroll (static buffer ptrs -> loop-invariant LDS addresses)
//  - K-read swizzle split: bofs[c] precomputed ((row&7)==(l31&7)), k2 -> imm
//  - tr16 via one base VGPR + compile-time offset: (T10/m162 pattern)
//  - defer-max (T13, shfl-based vote; xpartner NOT reintroduced)
//  - tree-shaped max & psum reductions (dep depth 32 -> 6; exact for max)
// ---------------------------------------------------------------------------
__global__ __launch_bounds__(256, 2) void attn(
    const unsigned short* __restrict__ Qm, const unsigned short* __restrict__ Km,
    const unsigned short* __restrict__ Vm, unsigned short* __restrict__ Ctx)
{
  constexpr int QB = 128, KVB = 64, NT = S_ / KVB;
  __shared__ unsigned short Qs[QB * DK_];      // 16 KB (swizzled rows)
  __shared__ unsigned short Kd[2][KVB * DK_];  // 2 x 8 KB (swizzled rows)
  __shared__ unsigned short Vd[2][KVB * DK_];  // 2 x 8 KB (subtiled for tr16)
  const int tid = threadIdx.x, lane = tid & 63, wave = tid >> 6;
  const int hi = lane >> 5, l31 = lane & 31, g1 = (lane >> 4) & 1;
  const int bh = blockIdx.y, q0 = blockIdx.x * QB;
  const int bq = bh >> 3, hh = bh & 7;
  const char* Qg = (const char*)(Qm + ((size_t)bq * S_ + q0) * D_ + hh * DK_);
  const char* Kg = (const char*)(Km + (size_t)bq * S_ * D_ + hh * DK_);
  const char* Vg = (const char*)(Vm + (size_t)bq * S_ * D_ + hh * DK_);

  // hoisted staging sources (K swizzled-rows; V subtiled) + LDS dest offsets
  const char* srcK[2];
  const char* srcV[2];
  int dstKV[2];
#pragma unroll
  for (int i = 0; i < 2; ++i) {
    int o = (wave * 2 + i) * 1024;
    int ol = o + lane * 16;
    {
      int row = ol >> 7, off = (ol ^ ((row & 7) << 4)) & 127;
      srcK[i] = Kg + (size_t)row * 1024 + off;
    }
    {
      int E0 = ol >> 1;
      int st = E0 >> 6, rr = (E0 >> 4) & 3, c0 = E0 & 15;
      int kk = (st >> 2) * 4 + rr, dd = (st & 3) * 16 + c0;
      srcV[i] = Vg + (size_t)kk * 1024 + dd * 2;
    }
    dstKV[i] = o;
  }

  // prologue: stage Q (128 rows, swizzled) + tile 0
#pragma unroll
  for (int i = 0; i < 4; ++i) {
    int o = (wave * 4 + i) * 1024;
    int ol = o + lane * 16;
    int row = ol >> 7, off = (ol ^ ((row & 7) << 4)) & 127;
    gld16(Qg + (size_t)row * 1024 + off, (char*)Qs + o);
  }
#pragma unroll
  for (int i = 0; i < 2; ++i) {
    gld16(srcK[i], (char*)Kd[0] + dstKV[i]);
    gld16(srcV[i], (char*)Vd[0] + dstKV[i]);
  }
  __syncthreads();

  // Q fragments (B-operand): row = wave*32 + l31, elems d = c*16 + hi*8 + e
  bf16x8 qf[4];
  {
    int row = wave * 32 + l31;
    int rb = row * 128, sw = (row & 7) << 4;
#pragma unroll
    for (int c = 0; c < 4; ++c)
      qf[c] = *(const bf16x8*)((const char*)Qs + ((rb + c * 32 + hi * 16) ^ sw));
  }

  // loop-invariant K-read column offsets: (c*32 + hi*16) ^ ((l31&7)<<4)
  // (valid split: XOR bits 4-6 are disjoint from k2*4096 + l31*128)
  int bofs[4];
  {
    const int swk = (l31 & 7) << 4;
#pragma unroll
    for (int c = 0; c < 4; ++c) bofs[c] = (c * 32 + hi * 16) ^ swk;
  }

  f32x16 oacc[2];
#pragma unroll
  for (int dt = 0; dt < 2; ++dt)
#pragma unroll
    for (int r = 0; r < 16; ++r) oacc[dt][r] = 0.f;
  float m2 = -1e30f, lsum = 0.f;
  constexpr float SCL2 = 0.125f * 1.44269504089f;  // 1/sqrt(DK) * log2(e)

  // att[2] carried state (tile t-1): zero so iter 0's PV adds nothing
  short4v va[4][2][2];
  bf16x8 pfrag[4];
#pragma unroll
  for (int c = 0; c < 4; ++c) {
#pragma unroll
    for (int dt = 0; dt < 2; ++dt) {
      va[c][dt][0] = short4v{0, 0, 0, 0};
      va[c][dt][1] = short4v{0, 0, 0, 0};
    }
    uint4v zz = {0u, 0u, 0u, 0u};
    pfrag[c] = __builtin_bit_cast(bf16x8, zz);
  }

  auto tile = [&](const unsigned short* Kbuf, const unsigned short* Vbuf,
                  unsigned short* KbufN, unsigned short* VbufN,
                  int tnext, bool doStage) {
    if (doStage) {
#pragma unroll
      for (int i = 0; i < 2; ++i) {
        gld16(srcK[i] + (size_t)tnext * 65536, (char*)KbufN + dstKV[i]);
        gld16(srcV[i] + (size_t)tnext * 65536, (char*)VbufN + dstKV[i]);
      }
    }

    // ---- swapped QK^T: sacc[k2] = K_tile * Q^T (S^T[k][q], q = l31) ----
    f32x16 sacc[2];
#pragma unroll
    for (int k2 = 0; k2 < 2; ++k2)
#pragma unroll
      for (int r = 0; r < 16; ++r) sacc[k2][r] = 0.f;
    const char* kb = (const char*)Kbuf + l31 * 128;
    __builtin_amdgcn_s_setprio(1);
#pragma unroll
    for (int c = 0; c < 4; ++c) {
      bf16x8 kf0 = *(const bf16x8*)(kb + bofs[c]);
      bf16x8 kf1 = *(const bf16x8*)(kb + bofs[c] + 4096);
      sacc[0] = mfma32(kf0, qf[c], sacc[0]);
      sacc[1] = mfma32(kf1, qf[c], sacc[1]);
    }
    // ---- PV(t-1): O^T += V^T * P ----
#pragma unroll
    for (int c = 0; c < 4; ++c)
#pragma unroll
      for (int dt = 0; dt < 2; ++dt) {
        short8v vv = __builtin_shufflevector(va[c][dt][0], va[c][dt][1],
                                             0, 1, 2, 3, 4, 5, 6, 7);
        oacc[dt] = mfma32(__builtin_bit_cast(bf16x8, vv), pfrag[c], oacc[dt]);
      }
    __builtin_amdgcn_s_setprio(0);

    // ---- online softmax(t): tree max + defer-max rescale (T13) ----
    float mx[16];
#pragma unroll
    for (int r = 0; r < 16; ++r) mx[r] = fmaxf(sacc[0][r], sacc[1][r]);
#pragma unroll
    for (int st = 8; st >= 1; st >>= 1)
#pragma unroll
      for (int r = 0; r < st; ++r) mx[r] = fmaxf(mx[r], mx[r + st]);
    float mloc = fmaxf(mx[0], __shfl_xor(mx[0], 32)) * SCL2;
    if (!__all(mloc <= m2 + 8.f)) {   // rare after tile 0: P bounded by 2^8
      float m2n = fmaxf(m2, mloc);
      float alpha = __builtin_amdgcn_exp2f(m2 - m2n);
      m2 = m2n;
      lsum *= alpha;
#pragma unroll
      for (int dt = 0; dt < 2; ++dt)
#pragma unroll
        for (int r = 0; r < 16; ++r) oacc[dt][r] *= alpha;
    }
    float ps[4] = {0.f, 0.f, 0.f, 0.f};
#pragma unroll
    for (int k2 = 0; k2 < 2; ++k2)
#pragma unroll
      for (int r = 0; r < 16; ++r) {
        float p = __builtin_amdgcn_exp2f(fmaf(sacc[k2][r], SCL2, -m2));
        sacc[k2][r] = p;
        ps[r & 3] += p;
      }
    float psum = (ps[0] + ps[1]) + (ps[2] + ps[3]);
    psum += __shfl_xor(psum, 32);
    lsum += psum;

    // ---- va(t): tr16 from base VGPR + imm offsets ----
    const char* vt = (const char*)Vbuf + hi * 1024 + g1 * 128 + (lane & 15) * 8;
#define TR16(c, dt)                                                    \
    va[c][dt][0] = tr16o<(c) * 2048 + (dt) * 256>(vt);                 \
    va[c][dt][1] = tr16o<(c) * 2048 + (dt) * 256 + 512>(vt);
    TR16(0, 0) TR16(0, 1) TR16(1, 0) TR16(1, 1)
    TR16(2, 0) TR16(2, 1) TR16(3, 0) TR16(3, 1)
#undef TR16

    // ---- pfrag(t) ----
#pragma unroll
    for (int c = 0; c < 4; ++c) {
      const f32x16& P = sacc[c >> 1];
      const int b = (c & 1) * 8;
      unsigned d0 = pkbf(P[b + 0], P[b + 1]);
      unsigned d1 = pkbf(P[b + 2], P[b + 3]);
      unsigned d2 = pkbf(P[b + 4], P[b + 5]);
      unsigned d3 = pkbf(P[b + 6], P[b + 7]);
      pl32swap(d0, d2);
      pl32swap(d1, d3);
      uint4v pi = {d0, d1, d2, d3};
      pfrag[c] = __builtin_bit_cast(bf16x8, pi);
    }

    __syncthreads();  // drains vm (next K/V staged) + lgkm (tr16 done)
  };

  for (int tb = 0; tb < NT; tb += 2) {
    tile(Kd[0], Vd[0], Kd[1], Vd[1], tb + 1, true);        // reads tile tb
    tile(Kd[1], Vd[1], Kd[0], Vd[0], tb + 2, tb + 2 < NT); // reads tile tb+1
  }

  // pending PV(NT-1)
  __builtin_amdgcn_s_setprio(1);
#pragma unroll
  for (int c = 0; c < 4; ++c)
#pragma unroll
    for (int dt = 0; dt < 2; ++dt) {
      short8v vv = __builtin_shufflevector(va[c][dt][0], va[c][dt][1],
                                           0, 1, 2, 3, 4, 5, 6, 7);
      oacc[dt] = mfma32(__builtin_bit_cast(bf16x8, vv), pfrag[c], oacc[dt]);
    }
  __builtin_amdgcn_s_setprio(0);

  // epilogue: O^T regs walk d; q = l31. d = dt*32 + 8g + 4hi + j (j=0..3)
  const float inv = 1.f / lsum;
  unsigned short* crow =
      Ctx + ((size_t)bq * S_ + q0 + wave * 32 + l31) * D_ + hh * DK_;
#pragma unroll
  for (int dt = 0; dt < 2; ++dt)
#pragma unroll
    for (int g = 0; g < 4; ++g) {
      uint2v pk;
      pk.x = pkbf(oacc[dt][4 * g + 0] * inv, oacc[dt][4 * g + 1] * inv);
      pk.y = pkbf(oacc[dt][4 * g + 2] * inv, oacc[dt][4 * g + 3] * inv);
      *(uint2v*)(crow + dt * 32 + 8 * g + 4 * hi) = pk;
    }
}

// ---------------------------------------------------------------------------
extern "C" void kernel_launch(void* const* d_in, const int* in_sizes, int n_in,
                              void* d_out, int out_size, void* d_ws, size_t ws_size,
                              hipStream_t stream) {
  const float* q  = (const float*)d_in[0];
  const float* k  = (const float*)d_in[1];
  const float* v  = (const float*)d_in[2];
  const float* wq = (const float*)d_in[3];
  const float* wk = (const float*)d_in[4];
  const float* wv = (const float*)d_in[5];
  const float* wo = (const float*)d_in[6];
  const float* bo = (const float*)d_in[7];
  float* out = (float*)d_out;

  constexpr size_t NX = (size_t)M_ * D_;
  constexpr size_t NW = (size_t)D_ * D_;
  char* ws = (char*)d_ws;
  unsigned short* Wqb = (unsigned short*)ws; ws += NW * 2;
  unsigned short* Wkb = (unsigned short*)ws; ws += NW * 2;
  unsigned short* Wvb = (unsigned short*)ws; ws += NW * 2;
  unsigned short* Wob = (unsigned short*)ws; ws += NW * 2;
  unsigned short* Qbf = (unsigned short*)ws; ws += NX * 2;
  unsigned short* Kbf = (unsigned short*)ws; ws += NX * 2;
  unsigned short* Vbf = (unsigned short*)ws; ws += NX * 2;
  unsigned short* Cx  = (unsigned short*)ws; ws += NX * 2;

  convert_w<<<1024, 256, 0, stream>>>(wq, wk, wv, wo, Wqb, Wkb, Wvb, Wob);
  gemm_qkv<<<dim3(4, 64, 3), 256, 0, stream>>>(
      q, k, v, Wqb, Wkb, Wvb, Qbf, Kbf, Vbf);
  attn<<<dim3(S_ / 128, B_ * H_), 256, 0, stream>>>(Qbf, Kbf, Vbf, Cx);
  gemm_out<<<dim3(4, 128), 256, 0, stream>>>(Cx, Wob, out, bo);
}